// Round 1
// baseline (1289.823 us; speedup 1.0000x reference)
//
// LoFTR encoder layer — MI355X / gfx950. Round 1: correctness-first full pipeline.
// Pipeline: prep weight transposes (bf16) -> QKV GEMMs -> KV reduce (2-stage) ->
// f9 + depthwise conv -> attn message -> merge+LN1 -> MLP1+relu -> MLP2+LN2 ->
// adapter down+relu -> adapter up + final combine.
// All big GEMMs: one templated MFMA row-block kernel (64 rows x BN cols, bf16 16x16x32).
#include <hip/hip_runtime.h>
#include <stdint.h>

#define LL 19200
#define NBATCH 4
#define NROWS (NBATCH * LL)   // 76800
#define HH 120
#define WW 160

typedef short bhalf8 __attribute__((ext_vector_type(8)));
typedef float f32x4 __attribute__((ext_vector_type(4)));

__device__ __forceinline__ float bfbits2f(uint32_t u) { union { uint32_t i; float f; } c; c.i = u << 16; return c.f; }
__device__ __forceinline__ float bf2f(uint16_t h) { return bfbits2f((uint32_t)h); }
__device__ __forceinline__ uint16_t f2bf(float f) {
    union { float f; uint32_t i; } c; c.f = f;
    return (uint16_t)((c.i + 0x7FFFu + ((c.i >> 16) & 1u)) >> 16);
}
__device__ __forceinline__ uint32_t pk2(uint16_t a, uint16_t b) { return (uint32_t)a | ((uint32_t)b << 16); }
__device__ __forceinline__ float elup1(float x) { return x > 0.f ? x + 1.f : expf(x); } // elu(x)+1

// ---------------- weight transpose to bf16 [out][in] ----------------
__global__ __launch_bounds__(256) void prep_wt(const float* __restrict__ src, uint16_t* __restrict__ dst,
                                               int K, int Nout) {
    int idx = blockIdx.x * 256 + threadIdx.x;
    if (idx >= K * Nout) return;
    int n = idx / K, kk = idx - n * K;
    dst[idx] = f2bf(src[(long)kk * Nout + n]);
}

// ---------------- row-block MFMA GEMM ----------------
// C[64 x BN] = A[64 x K] @ Wt^T   (Wt stored transposed: [out][in] bf16)
// MODE_A: 0 = single bf16 src (stride K), 1 = single f32 src (stride K),
//         2 = concat: cols 0..255 from f32 A0f (stride 256), 256..511 from bf16 A1b (stride 256)
// EPI: 0 none, 1 relu, 2 layernorm (BN==256, grid.y==1), 3 final combine (writes f32 d_out)
#define EPI_NONE 0
#define EPI_RELU 1
#define EPI_LN 2
#define EPI_FINAL 3

template<int BN, int MODE_A, int EPI>
__global__ __launch_bounds__(256)
void gemm_rb(const float* __restrict__ A0f, const uint16_t* __restrict__ A0b,
             const uint16_t* __restrict__ A1b,
             const uint16_t* __restrict__ Wt, int K,
             uint16_t* __restrict__ outb, float* __restrict__ outf, int outW,
             const float* __restrict__ lnw, const float* __restrict__ lnb,
             const float* __restrict__ xres, const uint16_t* __restrict__ msg2res,
             const uint16_t* __restrict__ convres, const float* __restrict__ ratep)
{
    constexpr int NT = BN / 16;
    __shared__ __align__(16) uint16_t a_sm[64 * 40];   // row stride 40 (80B) breaks bank aliasing
    __shared__ __align__(16) uint16_t w_sm[BN * 40];
    const int tid = threadIdx.x;
    const int lane = tid & 63;
    const int wv = tid >> 6;
    const long row0 = (long)blockIdx.x * 64;
    const int col0 = blockIdx.y * BN;

    f32x4 acc[NT];
#pragma unroll
    for (int t = 0; t < NT; ++t) acc[t] = (f32x4){0.f, 0.f, 0.f, 0.f};

    const int ar = tid >> 2;
    const int ac8 = (tid & 3) * 8;
    const long arg = row0 + ar;

    for (int k0 = 0; k0 < K; k0 += 32) {
        // stage A tile (64x32 bf16)
        {
            int ka = k0 + ac8;
            uint4 stg;
            if (MODE_A == 0) {
                stg = *(const uint4*)(A0b + arg * (long)K + ka);
            } else if (MODE_A == 1) {
                const float* p = A0f + arg * (long)K + ka;
                float4 lo = *(const float4*)p;
                float4 hi = *(const float4*)(p + 4);
                stg.x = pk2(f2bf(lo.x), f2bf(lo.y)); stg.y = pk2(f2bf(lo.z), f2bf(lo.w));
                stg.z = pk2(f2bf(hi.x), f2bf(hi.y)); stg.w = pk2(f2bf(hi.z), f2bf(hi.w));
            } else {
                if (ka < 256) {
                    const float* p = A0f + arg * 256 + ka;
                    float4 lo = *(const float4*)p;
                    float4 hi = *(const float4*)(p + 4);
                    stg.x = pk2(f2bf(lo.x), f2bf(lo.y)); stg.y = pk2(f2bf(lo.z), f2bf(lo.w));
                    stg.z = pk2(f2bf(hi.x), f2bf(hi.y)); stg.w = pk2(f2bf(hi.z), f2bf(hi.w));
                } else {
                    stg = *(const uint4*)(A1b + arg * 256 + (ka - 256));
                }
            }
            *(uint4*)&a_sm[ar * 40 + ac8] = stg;
        }
        // stage W tile (BN x 32 bf16) from transposed weights
        for (int idx = tid; idx < BN * 4; idx += 256) {
            int c = idx >> 2, seg = idx & 3;
            *(uint4*)&w_sm[c * 40 + seg * 8] =
                *(const uint4*)(Wt + (long)(col0 + c) * K + k0 + seg * 8);
        }
        __syncthreads();
        bhalf8 af = *(const bhalf8*)&a_sm[(wv * 16 + (lane & 15)) * 40 + (lane >> 4) * 8];
#pragma unroll
        for (int t = 0; t < NT; ++t) {
            bhalf8 bfr = *(const bhalf8*)&w_sm[(t * 16 + (lane & 15)) * 40 + (lane >> 4) * 8];
            acc[t] = __builtin_amdgcn_mfma_f32_16x16x32_bf16(af, bfr, acc[t], 0, 0, 0);
        }
        __syncthreads();
    }

    const int cl = lane & 15;
    const int rg4 = (lane >> 4) * 4;

    if (EPI == EPI_LN) {
#pragma unroll
        for (int j = 0; j < 4; ++j) {
            float s = 0.f, ss = 0.f;
#pragma unroll
            for (int t = 0; t < NT; ++t) { float vv = acc[t][j]; s += vv; ss += vv * vv; }
#pragma unroll
            for (int m = 1; m < 16; m <<= 1) { s += __shfl_xor(s, m, 64); ss += __shfl_xor(ss, m, 64); }
            float mu = s * (1.f / 256.f);
            float var = ss * (1.f / 256.f) - mu * mu;
            float rstd = rsqrtf(var + 1e-5f);
            long rowg = row0 + wv * 16 + rg4 + j;
#pragma unroll
            for (int t = 0; t < NT; ++t) {
                int col = t * 16 + cl;
                float vv = (acc[t][j] - mu) * rstd * lnw[col] + lnb[col];
                outb[rowg * (long)outW + col] = f2bf(vv);
            }
        }
    } else if (EPI == EPI_FINAL) {
        float rate = ratep[0];
#pragma unroll
        for (int j = 0; j < 4; ++j) {
            long rowg = row0 + wv * 16 + rg4 + j;
            int bb = (int)(rowg / LL);
            int ll = (int)(rowg - (long)bb * LL);
#pragma unroll
            for (int t = 0; t < NT; ++t) {
                int col = t * 16 + cl;
                long o = rowg * 256 + col;
                float xv = xres[o];
                float m2 = bf2f(msg2res[o]);
                float cv = bf2f(convres[((long)(bb * 256 + col)) * LL + ll]);
                outf[o] = xv + m2 + 0.1f * acc[t][j] + rate * cv;
            }
        }
    } else {
#pragma unroll
        for (int j = 0; j < 4; ++j) {
            long rowg = row0 + wv * 16 + rg4 + j;
#pragma unroll
            for (int t = 0; t < NT; ++t) {
                int col = col0 + t * 16 + cl;
                float vv = acc[t][j];
                if (EPI == EPI_RELU) vv = vv > 0.f ? vv : 0.f;
                outb[rowg * (long)outW + col] = f2bf(vv);
            }
        }
    }
}

// ---------------- linear attention: stage 1 partial KV / Ksum ----------------
// grid (75 chunks, 32 bh); each block reduces 256 source rows.
__global__ __launch_bounds__(256)
void kv_partial(const uint16_t* __restrict__ kb, const uint16_t* __restrict__ vb,
                float* __restrict__ part) {
    __shared__ float kf_sm[32][33];
    __shared__ float v_sm[32][33];
    const int tid = threadIdx.x;
    const int bh = blockIdx.y, b = bh >> 3, h = bh & 7;
    const int s0 = blockIdx.x * 256;
    const int d = tid >> 3, vg = tid & 7;
    const int sl = tid >> 3, e4 = (tid & 7) * 4;
    float a0 = 0.f, a1 = 0.f, a2 = 0.f, a3 = 0.f, aKs = 0.f;
    for (int it = 0; it < 8; ++it) {
        long base = ((long)(b * LL + s0 + it * 32 + sl)) * 256 + h * 32 + e4;
        uint2 kk = *(const uint2*)(kb + base);
        uint2 vv = *(const uint2*)(vb + base);
        kf_sm[sl][e4 + 0] = elup1(bfbits2f(kk.x & 0xFFFFu));
        kf_sm[sl][e4 + 1] = elup1(bfbits2f(kk.x >> 16));
        kf_sm[sl][e4 + 2] = elup1(bfbits2f(kk.y & 0xFFFFu));
        kf_sm[sl][e4 + 3] = elup1(bfbits2f(kk.y >> 16));
        v_sm[sl][e4 + 0] = bfbits2f(vv.x & 0xFFFFu);
        v_sm[sl][e4 + 1] = bfbits2f(vv.x >> 16);
        v_sm[sl][e4 + 2] = bfbits2f(vv.y & 0xFFFFu);
        v_sm[sl][e4 + 3] = bfbits2f(vv.y >> 16);
        __syncthreads();
#pragma unroll 8
        for (int s = 0; s < 32; ++s) {
            float kf = kf_sm[s][d];
            aKs += kf;
            const float* vp = &v_sm[s][vg * 4];
            a0 += kf * vp[0]; a1 += kf * vp[1]; a2 += kf * vp[2]; a3 += kf * vp[3];
        }
        __syncthreads();
    }
    long pb = ((long)(blockIdx.x * 32 + bh)) * 1056;
    part[pb + d * 32 + vg * 4 + 0] = a0;
    part[pb + d * 32 + vg * 4 + 1] = a1;
    part[pb + d * 32 + vg * 4 + 2] = a2;
    part[pb + d * 32 + vg * 4 + 3] = a3;
    if (vg == 0) part[pb + 1024 + d] = aKs;
}

// stage 2: reduce 75 partials -> KV (unscaled) + Ksum
__global__ __launch_bounds__(256)
void kv_final(const float* __restrict__ part, float* __restrict__ KVg, float* __restrict__ Ksum) {
    const int bh = blockIdx.x, tid = threadIdx.x;
    for (int idx = tid; idx < 1056; idx += 256) {
        float s = 0.f;
        for (int c = 0; c < 75; ++c) s += part[((long)(c * 32 + bh)) * 1056 + idx];
        if (idx < 1024) KVg[bh * 1024 + idx] = s;
        else Ksum[bh * 32 + idx - 1024] = s;
    }
}

// ---------------- attn message: msg = (Qf @ KV) * Z ----------------
__global__ __launch_bounds__(256)
void attn_msg(const uint16_t* __restrict__ qb, const float* __restrict__ KVg,
              const float* __restrict__ Ksum, uint16_t* __restrict__ msgout) {
    __shared__ float kv_sm[8192];
    __shared__ float ks_sm[256];
    __shared__ float qf_sm[8][264];
    const int tid = threadIdx.x;
    const int b = blockIdx.y;
    const long l0 = (long)blockIdx.x * 64;
    for (int idx = tid; idx < 8192; idx += 256) kv_sm[idx] = KVg[b * 8192 + idx];
    ks_sm[tid] = Ksum[b * 256 + tid];
    __syncthreads();
    const int h = tid >> 5, vc = tid & 31;
    const int rr = tid >> 5, e8 = (tid & 31) * 8;
    for (int r0 = 0; r0 < 64; r0 += 8) {
        long rowg = (long)b * LL + l0 + r0 + rr;
        uint4 qv = *(const uint4*)(qb + rowg * 256 + e8);
        qf_sm[rr][e8 + 0] = elup1(bfbits2f(qv.x & 0xFFFFu));
        qf_sm[rr][e8 + 1] = elup1(bfbits2f(qv.x >> 16));
        qf_sm[rr][e8 + 2] = elup1(bfbits2f(qv.y & 0xFFFFu));
        qf_sm[rr][e8 + 3] = elup1(bfbits2f(qv.y >> 16));
        qf_sm[rr][e8 + 4] = elup1(bfbits2f(qv.z & 0xFFFFu));
        qf_sm[rr][e8 + 5] = elup1(bfbits2f(qv.z >> 16));
        qf_sm[rr][e8 + 6] = elup1(bfbits2f(qv.w & 0xFFFFu));
        qf_sm[rr][e8 + 7] = elup1(bfbits2f(qv.w >> 16));
        __syncthreads();
        for (int r2 = 0; r2 < 8; ++r2) {
            float p = qf_sm[r2][h * 32 + vc] * ks_sm[h * 32 + vc];
#pragma unroll
            for (int m = 1; m < 32; m <<= 1) p += __shfl_xor(p, m, 64);
            float Z = 1.f / (p + 1e-6f);
            float acc = 0.f;
#pragma unroll
            for (int dd = 0; dd < 32; ++dd)
                acc += qf_sm[r2][h * 32 + dd] * kv_sm[(h * 32 + dd) * 32 + vc];
            long orow = (long)b * LL + l0 + r0 + r2;
            msgout[orow * 256 + tid] = f2bf(acc * Z);
        }
        __syncthreads();
    }
}

// ---------------- conv branch: f9 1x1 projection (24 -> 9 per (l, d')) ----------------
__global__ __launch_bounds__(256)
void f9_kernel(const uint16_t* __restrict__ qb, const uint16_t* __restrict__ kb,
               const uint16_t* __restrict__ vb, const float* __restrict__ fcw,
               const float* __restrict__ fcb, uint16_t* __restrict__ fconv) {
    __shared__ __align__(16) uint16_t sm[3][32][264];
    __shared__ float fw[9][24];
    __shared__ float fb[9];
    const int tid = threadIdx.x;
    const int b = blockIdx.y;
    const int l0 = blockIdx.x * 32;
    if (tid < 216) fw[tid / 24][tid % 24] = fcw[tid];
    if (tid >= 216 && tid < 225) fb[tid - 216] = fcb[tid - 216];
    for (int idx = tid; idx < 3072; idx += 256) {
        int tsr = idx >> 10, rem = idx & 1023, row = rem >> 5, c8 = (rem & 31) * 8;
        const uint16_t* src = tsr == 0 ? qb : (tsr == 1 ? kb : vb);
        *(uint4*)&sm[tsr][row][c8] = *(const uint4*)(src + ((long)(b * LL + l0 + row)) * 256 + c8);
    }
    __syncthreads();
    for (int idx = tid; idx < 9216; idx += 256) {
        int ch = idx >> 5, li = idx & 31;
        int dp = ch / 9, o = ch - dp * 9;
        float acc = fb[o];
#pragma unroll
        for (int hd = 0; hd < 8; ++hd) {
            int cb = hd * 32 + dp;
            acc += fw[o][3 * hd + 0] * bf2f(sm[0][li][cb]);
            acc += fw[o][3 * hd + 1] * bf2f(sm[1][li][cb]);
            acc += fw[o][3 * hd + 2] * bf2f(sm[2][li][cb]);
        }
        fconv[((long)(b * 288 + ch)) * LL + l0 + li] = f2bf(acc);
    }
}

// ---------------- depthwise-grouped 3x3 conv (groups=32, 9 in / 8 out per group) --------
__global__ __launch_bounds__(256)
void dwconv(const uint16_t* __restrict__ fconv, const float* __restrict__ depw,
            const float* __restrict__ depb, uint16_t* __restrict__ convout) {
    __shared__ float in_sm[9][3][34];
    __shared__ float w_sm[8][81];
    __shared__ float b_sm[8];
    const int tid = threadIdx.x;
    const int b = blockIdx.z, g = blockIdx.y;
    const int y = blockIdx.x / 5, x0 = (blockIdx.x % 5) * 32;
    for (int idx = tid; idx < 648; idx += 256)
        w_sm[idx / 81][idx % 81] = depw[(long)(g * 8) * 81 + idx];
    if (tid < 8) b_sm[tid] = depb[g * 8 + tid];
    for (int idx = tid; idx < 918; idx += 256) {
        int i = idx / 102, rem = idx - i * 102, ry = rem / 34, rx = rem - ry * 34;
        int yy = y + ry - 1, xx = x0 + rx - 1;
        float v = 0.f;
        if (yy >= 0 && yy < HH && xx >= 0 && xx < WW)
            v = bf2f(fconv[((long)(b * 288 + g * 9 + i)) * LL + yy * WW + xx]);
        in_sm[i][ry][rx] = v;
    }
    __syncthreads();
    const int xi = tid & 31, m = tid >> 5;
    float acc = b_sm[m];
#pragma unroll
    for (int i = 0; i < 9; ++i)
#pragma unroll
        for (int ky = 0; ky < 3; ++ky)
#pragma unroll
            for (int kx = 0; kx < 3; ++kx)
                acc += w_sm[m][i * 9 + ky * 3 + kx] * in_sm[i][ky][xi + kx];
    convout[((long)(b * 256 + g * 8 + m)) * LL + y * WW + x0 + xi] = f2bf(acc);
}

// ---------------- launcher ----------------
extern "C" void kernel_launch(void* const* d_in, const int* in_sizes, int n_in,
                              void* d_out, int out_size, void* d_ws, size_t ws_size,
                              hipStream_t stream) {
    (void)in_sizes; (void)n_in; (void)out_size; (void)ws_size;
    const float* x      = (const float*)d_in[0];
    const float* src    = (const float*)d_in[1];
    const float* Wq     = (const float*)d_in[2];
    const float* Wk     = (const float*)d_in[3];
    const float* Wv     = (const float*)d_in[4];
    const float* Wmerge = (const float*)d_in[5];
    const float* Wmlp1  = (const float*)d_in[6];
    const float* Wmlp2  = (const float*)d_in[7];
    const float* ln1w   = (const float*)d_in[8];
    const float* ln1b   = (const float*)d_in[9];
    const float* ln2w   = (const float*)d_in[10];
    const float* ln2b   = (const float*)d_in[11];
    const float* Wdown  = (const float*)d_in[12];
    const float* Wup    = (const float*)d_in[13];
    const float* fcw    = (const float*)d_in[14];
    const float* fcb    = (const float*)d_in[15];
    const float* depw   = (const float*)d_in[16];
    const float* depb   = (const float*)d_in[17];
    const float* rate   = (const float*)d_in[18];

    char* ws = (char*)d_ws;
    const size_t SZ_NB = (size_t)NROWS * 256 * 2;            // 39,321,600
    const size_t O_Q = 0;
    const size_t O_K = SZ_NB;
    const size_t O_V = 2 * SZ_NB;
    const size_t O_FCONV = 3 * SZ_NB;                        // 44,236,800 bytes
    const size_t O_CONVOUT = O_FCONV + (size_t)NBATCH * 288 * LL * 2;
    const size_t O_PART = O_CONVOUT + SZ_NB;                 // 10,137,600 bytes
    const size_t O_KV = O_PART + (size_t)75 * 32 * 1056 * 4;
    const size_t O_KS = O_KV + (size_t)32 * 1024 * 4;
    const size_t O_WT = O_KS + (size_t)32 * 32 * 4;

    uint16_t* qB      = (uint16_t*)(ws + O_Q);
    uint16_t* kB      = (uint16_t*)(ws + O_K);
    uint16_t* vB      = (uint16_t*)(ws + O_V);
    uint16_t* fconv   = (uint16_t*)(ws + O_FCONV);
    uint16_t* convout = (uint16_t*)(ws + O_CONVOUT);
    float*    part    = (float*)(ws + O_PART);
    float*    KVg     = (float*)(ws + O_KV);
    float*    Ksg     = (float*)(ws + O_KS);
    uint16_t* wt_q    = (uint16_t*)(ws + O_WT);
    uint16_t* wt_k    = wt_q + 256 * 256;
    uint16_t* wt_v    = wt_k + 256 * 256;
    uint16_t* wt_m    = wt_v + 256 * 256;
    uint16_t* wt_m1   = wt_m + 256 * 256;
    uint16_t* wt_m2   = wt_m1 + 512 * 512;
    uint16_t* wt_d    = wt_m2 + 512 * 256;
    uint16_t* wt_u    = wt_d + 512 * 64;
    // aliases (lifetimes verified against launch order):
    uint16_t* msgattn = kB;                    // written by attn_msg after k is dead
    uint16_t* msgB    = vB;                    // LN1 output over v
    uint16_t* hidden  = qB;                    // MLP hidden (N x 512) spans q+k regions
    uint16_t* msg2    = fconv;                 // LN2 output over f_conv
    uint16_t* h2      = (uint16_t*)(ws + O_PART); // adapter hidden over partials

    // --- weight prep (transposed bf16) ---
    prep_wt<<<256, 256, 0, stream>>>(Wq, wt_q, 256, 256);
    prep_wt<<<256, 256, 0, stream>>>(Wk, wt_k, 256, 256);
    prep_wt<<<256, 256, 0, stream>>>(Wv, wt_v, 256, 256);
    prep_wt<<<256, 256, 0, stream>>>(Wmerge, wt_m, 256, 256);
    prep_wt<<<1024, 256, 0, stream>>>(Wmlp1, wt_m1, 512, 512);
    prep_wt<<<512, 256, 0, stream>>>(Wmlp2, wt_m2, 512, 256);
    prep_wt<<<128, 256, 0, stream>>>(Wdown, wt_d, 512, 64);
    prep_wt<<<64, 256, 0, stream>>>(Wup, wt_u, 64, 256);

    const dim3 g1200(NROWS / 64, 1);
    // --- QKV ---
    gemm_rb<256, 1, EPI_NONE><<<g1200, 256, 0, stream>>>(x, nullptr, nullptr, wt_q, 256, qB, nullptr, 256,
        nullptr, nullptr, nullptr, nullptr, nullptr, nullptr);
    gemm_rb<256, 1, EPI_NONE><<<g1200, 256, 0, stream>>>(src, nullptr, nullptr, wt_k, 256, kB, nullptr, 256,
        nullptr, nullptr, nullptr, nullptr, nullptr, nullptr);
    gemm_rb<256, 1, EPI_NONE><<<g1200, 256, 0, stream>>>(src, nullptr, nullptr, wt_v, 256, vB, nullptr, 256,
        nullptr, nullptr, nullptr, nullptr, nullptr, nullptr);
    // --- linear attention KV reduce ---
    kv_partial<<<dim3(75, 32), 256, 0, stream>>>(kB, vB, part);
    kv_final<<<32, 256, 0, stream>>>(part, KVg, Ksg);
    // --- conv branch ---
    f9_kernel<<<dim3(LL / 32, NBATCH), 256, 0, stream>>>(qB, kB, vB, fcw, fcb, fconv);
    dwconv<<<dim3(600, 32, NBATCH), 256, 0, stream>>>(fconv, depw, depb, convout);
    // --- attention message (k,v now dead; write over k region) ---
    attn_msg<<<dim3(LL / 64, NBATCH), 256, 0, stream>>>(qB, KVg, Ksg, msgattn);
    // --- merge + LN1 ---
    gemm_rb<256, 0, EPI_LN><<<g1200, 256, 0, stream>>>(nullptr, msgattn, nullptr, wt_m, 256, msgB, nullptr, 256,
        ln1w, ln1b, nullptr, nullptr, nullptr, nullptr);
    // --- MLP1 + relu (writes hidden over q/k regions; reads x + msgB) ---
    gemm_rb<256, 2, EPI_RELU><<<dim3(NROWS / 64, 2), 256, 0, stream>>>(x, nullptr, msgB, wt_m1, 512, hidden, nullptr, 512,
        nullptr, nullptr, nullptr, nullptr, nullptr, nullptr);
    // --- MLP2 + LN2 ---
    gemm_rb<256, 0, EPI_LN><<<g1200, 256, 0, stream>>>(nullptr, hidden, nullptr, wt_m2, 512, msg2, nullptr, 256,
        ln2w, ln2b, nullptr, nullptr, nullptr, nullptr);
    // --- adapter down + relu ---
    gemm_rb<64, 2, EPI_RELU><<<g1200, 256, 0, stream>>>(x, nullptr, msg2, wt_d, 512, h2, nullptr, 64,
        nullptr, nullptr, nullptr, nullptr, nullptr, nullptr);
    // --- adapter up + final combine ---
    gemm_rb<256, 0, EPI_FINAL><<<g1200, 256, 0, stream>>>(nullptr, h2, nullptr, wt_u, 64, nullptr, (float*)d_out, 256,
        nullptr, nullptr, x, msg2, convout, rate);
}

// Round 2
// 956.849 us; speedup vs baseline: 1.3480x; 1.3480x over previous
//
// LoFTR encoder layer — MI355X / gfx950. Round 2: dwconv register-tile rewrite +
// 128x256 MFMA GEMM with global_load_lds staging (m97-class structure).
#include <hip/hip_runtime.h>
#include <stdint.h>

#define LL 19200
#define NBATCH 4
#define NROWS (NBATCH * LL)   // 76800
#define HH 120
#define WW 160

typedef short bhalf8 __attribute__((ext_vector_type(8)));
typedef float f32x4 __attribute__((ext_vector_type(4)));

__device__ __forceinline__ float bfbits2f(uint32_t u) { union { uint32_t i; float f; } c; c.i = u << 16; return c.f; }
__device__ __forceinline__ float bf2f(uint16_t h) { return bfbits2f((uint32_t)h); }
__device__ __forceinline__ uint16_t f2bf(float f) {
    union { float f; uint32_t i; } c; c.f = f;
    return (uint16_t)((c.i + 0x7FFFu + ((c.i >> 16) & 1u)) >> 16);
}
__device__ __forceinline__ uint32_t pk2(uint16_t a, uint16_t b) { return (uint32_t)a | ((uint32_t)b << 16); }
__device__ __forceinline__ float elup1(float x) { return x > 0.f ? x + 1.f : expf(x); } // elu(x)+1

__device__ __forceinline__ uint4 pack8f(const float* p) {
    float4 lo = *(const float4*)p; float4 hi = *(const float4*)(p + 4);
    uint4 s;
    s.x = pk2(f2bf(lo.x), f2bf(lo.y)); s.y = pk2(f2bf(lo.z), f2bf(lo.w));
    s.z = pk2(f2bf(hi.x), f2bf(hi.y)); s.w = pk2(f2bf(hi.z), f2bf(hi.w));
    return s;
}

// async global->LDS, 16B per lane; lds dst must be wave-uniform base (lane*16 added by HW)
__device__ __forceinline__ void gll16(const void* g, void* l) {
    __builtin_amdgcn_global_load_lds((const __attribute__((address_space(1))) uint32_t*)g,
                                     (__attribute__((address_space(3))) uint32_t*)l, 16, 0, 0);
}

// ---------------- weight transpose to bf16 [out][in] ----------------
__global__ __launch_bounds__(256) void prep_wt(const float* __restrict__ src, uint16_t* __restrict__ dst,
                                               int K, int Nout) {
    int idx = blockIdx.x * 256 + threadIdx.x;
    if (idx >= K * Nout) return;
    int n = idx / K, kk = idx - n * K;
    dst[idx] = f2bf(src[(long)kk * Nout + n]);
}

// ---------------- 128xBN MFMA GEMM, 512 threads, 8 waves ----------------
// C[128 x BN] = A[128 x K] @ Wt^T  (Wt: [out][in] bf16)
// MODE_A: 0 = bf16 A0b stride K; 1 = f32 A0f stride K; 2 = concat f32 A0f(256) | bf16 A1b(256)
#define EPI_NONE 0
#define EPI_RELU 1
#define EPI_LN 2
#define EPI_FINAL 3

template<int BN, int MODE_A, int EPI>
__global__ __launch_bounds__(512)
void gemm_big(const float* __restrict__ A0f, const uint16_t* __restrict__ A0b,
              const uint16_t* __restrict__ A1b,
              const uint16_t* __restrict__ Wt, int K,
              uint16_t* __restrict__ outb, float* __restrict__ outf, int outW,
              const float* __restrict__ lnw, const float* __restrict__ lnb,
              const float* __restrict__ xres, const uint16_t* __restrict__ msg2res,
              const uint16_t* __restrict__ convres, const float* __restrict__ ratep)
{
    constexpr int WCOLS = BN / 64;            // 4 (BN=256) or 1 (BN=64)
    constexpr int WROWS = 8 / WCOLS;          // 2 or 8
    constexpr int MT = 128 / (WROWS * 16);    // 4 or 1
    __shared__ __align__(16) uint16_t a_sm[128 * 32];
    __shared__ __align__(16) uint16_t b_sm[BN * 32];
    const int tid = threadIdx.x;
    const int lane = tid & 63;
    const int wv = tid >> 6;
    const int wr = wv / WCOLS, wc = wv % WCOLS;
    const long row0 = (long)blockIdx.x * 128;
    const int col0 = blockIdx.y * BN;

    f32x4 acc[MT][4];
#pragma unroll
    for (int m = 0; m < MT; ++m)
#pragma unroll
        for (int n = 0; n < 4; ++n) acc[m][n] = (f32x4){0.f, 0.f, 0.f, 0.f};

    const int sr = tid >> 2;          // 0..127
    const int sc = (tid & 3) * 8;     // 0,8,16,24
    const long argA = row0 + sr;
    uint16_t* a_dst = a_sm + (tid >> 6) * 512;          // wave-uniform
    uint16_t* b_dst = b_sm + (tid >> 6) * 512;

    for (int k0 = 0; k0 < K; k0 += 32) {
        // ---- stage A (128x32 bf16 = 8KB) ----
        if (MODE_A == 0) {
            gll16(A0b + argA * (long)K + k0 + sc, a_dst);
        } else if (MODE_A == 1) {
            *(uint4*)&a_sm[sr * 32 + sc] = pack8f(A0f + argA * (long)K + k0 + sc);
        } else {
            if (k0 < 256) *(uint4*)&a_sm[sr * 32 + sc] = pack8f(A0f + argA * 256 + k0 + sc);
            else          gll16(A1b + argA * 256 + (k0 - 256) + sc, a_dst);
        }
        // ---- stage B (BNx32 bf16) ----
        if (BN == 256) {
            gll16(Wt + (long)(col0 + sr) * K + k0 + sc, b_dst);
            gll16(Wt + (long)(col0 + 128 + sr) * K + k0 + sc, b_sm + 4096 + (tid >> 6) * 512);
        } else {
            if (tid < 256) gll16(Wt + (long)(col0 + sr) * K + k0 + sc, b_dst);
        }
        __syncthreads();
        bhalf8 af[MT];
#pragma unroll
        for (int m = 0; m < MT; ++m)
            af[m] = *(const bhalf8*)&a_sm[(wr * MT * 16 + m * 16 + (lane & 15)) * 32 + (lane >> 4) * 8];
#pragma unroll
        for (int n = 0; n < 4; ++n) {
            bhalf8 bfr = *(const bhalf8*)&b_sm[(wc * 64 + n * 16 + (lane & 15)) * 32 + (lane >> 4) * 8];
#pragma unroll
            for (int m = 0; m < MT; ++m)
                acc[m][n] = __builtin_amdgcn_mfma_f32_16x16x32_bf16(af[m], bfr, acc[m][n], 0, 0, 0);
        }
        __syncthreads();
    }

    const int cl = lane & 15;
    const int rg4 = (lane >> 4) * 4;

    if constexpr (EPI == EPI_LN) {
        // cross-wave LN over 256 cols (4 wc waves x 64 cols). grid.y==1, outW==256.
        __shared__ float red_s[4][128];
        __shared__ float red_ss[4][128];
#pragma unroll
        for (int m = 0; m < MT; ++m)
#pragma unroll
            for (int j = 0; j < 4; ++j) {
                float p = 0.f, pp = 0.f;
#pragma unroll
                for (int n = 0; n < 4; ++n) { float v = acc[m][n][j]; p += v; pp += v * v; }
#pragma unroll
                for (int msk = 1; msk < 16; msk <<= 1) { p += __shfl_xor(p, msk, 64); pp += __shfl_xor(pp, msk, 64); }
                if (cl == 0) {
                    int lr = wr * 64 + m * 16 + rg4 + j;
                    red_s[wc][lr] = p; red_ss[wc][lr] = pp;
                }
            }
        __syncthreads();
#pragma unroll
        for (int m = 0; m < MT; ++m)
#pragma unroll
            for (int j = 0; j < 4; ++j) {
                int lr = wr * 64 + m * 16 + rg4 + j;
                float s = red_s[0][lr] + red_s[1][lr] + red_s[2][lr] + red_s[3][lr];
                float ss = red_ss[0][lr] + red_ss[1][lr] + red_ss[2][lr] + red_ss[3][lr];
                float mu = s * (1.f / 256.f);
                float var = ss * (1.f / 256.f) - mu * mu;
                float rstd = rsqrtf(var + 1e-5f);
                long rowg = row0 + lr;
#pragma unroll
                for (int n = 0; n < 4; ++n) {
                    int col = wc * 64 + n * 16 + cl;
                    float vv = (acc[m][n][j] - mu) * rstd * lnw[col] + lnb[col];
                    outb[rowg * (long)outW + col] = f2bf(vv);
                }
            }
    } else if constexpr (EPI == EPI_FINAL) {
        float rate = ratep[0];
#pragma unroll
        for (int m = 0; m < MT; ++m)
#pragma unroll
            for (int j = 0; j < 4; ++j) {
                long rowg = row0 + wr * MT * 16 + m * 16 + rg4 + j;
                int bb = (int)(rowg / LL);
                int ll = (int)(rowg - (long)bb * LL);
#pragma unroll
                for (int n = 0; n < 4; ++n) {
                    int col = wc * 64 + n * 16 + cl;
                    long o = rowg * 256 + col;
                    float xv = xres[o];
                    float m2 = bf2f(msg2res[o]);
                    float cv = bf2f(convres[((long)(bb * 256 + col)) * LL + ll]);
                    outf[o] = xv + m2 + 0.1f * acc[m][n][j] + rate * cv;
                }
            }
    } else {
#pragma unroll
        for (int m = 0; m < MT; ++m)
#pragma unroll
            for (int j = 0; j < 4; ++j) {
                long rowg = row0 + wr * MT * 16 + m * 16 + rg4 + j;
#pragma unroll
                for (int n = 0; n < 4; ++n) {
                    int col = col0 + wc * 64 + n * 16 + cl;
                    float vv = acc[m][n][j];
                    if (EPI == EPI_RELU) vv = vv > 0.f ? vv : 0.f;
                    outb[rowg * (long)outW + col] = f2bf(vv);
                }
            }
    }
}

// ---------------- linear attention: stage 1 partial KV / Ksum ----------------
__global__ __launch_bounds__(256)
void kv_partial(const uint16_t* __restrict__ kb, const uint16_t* __restrict__ vb,
                float* __restrict__ part) {
    __shared__ float kf_sm[32][33];
    __shared__ float v_sm[32][33];
    const int tid = threadIdx.x;
    const int bh = blockIdx.y, b = bh >> 3, h = bh & 7;
    const int s0 = blockIdx.x * 256;
    const int d = tid >> 3, vg = tid & 7;
    const int sl = tid >> 3, e4 = (tid & 7) * 4;
    float a0 = 0.f, a1 = 0.f, a2 = 0.f, a3 = 0.f, aKs = 0.f;
    for (int it = 0; it < 8; ++it) {
        long base = ((long)(b * LL + s0 + it * 32 + sl)) * 256 + h * 32 + e4;
        uint2 kk = *(const uint2*)(kb + base);
        uint2 vv = *(const uint2*)(vb + base);
        kf_sm[sl][e4 + 0] = elup1(bfbits2f(kk.x & 0xFFFFu));
        kf_sm[sl][e4 + 1] = elup1(bfbits2f(kk.x >> 16));
        kf_sm[sl][e4 + 2] = elup1(bfbits2f(kk.y & 0xFFFFu));
        kf_sm[sl][e4 + 3] = elup1(bfbits2f(kk.y >> 16));
        v_sm[sl][e4 + 0] = bfbits2f(vv.x & 0xFFFFu);
        v_sm[sl][e4 + 1] = bfbits2f(vv.x >> 16);
        v_sm[sl][e4 + 2] = bfbits2f(vv.y & 0xFFFFu);
        v_sm[sl][e4 + 3] = bfbits2f(vv.y >> 16);
        __syncthreads();
#pragma unroll 8
        for (int s = 0; s < 32; ++s) {
            float kf = kf_sm[s][d];
            aKs += kf;
            const float* vp = &v_sm[s][vg * 4];
            a0 += kf * vp[0]; a1 += kf * vp[1]; a2 += kf * vp[2]; a3 += kf * vp[3];
        }
        __syncthreads();
    }
    long pb = ((long)(blockIdx.x * 32 + bh)) * 1056;
    part[pb + d * 32 + vg * 4 + 0] = a0;
    part[pb + d * 32 + vg * 4 + 1] = a1;
    part[pb + d * 32 + vg * 4 + 2] = a2;
    part[pb + d * 32 + vg * 4 + 3] = a3;
    if (vg == 0) part[pb + 1024 + d] = aKs;
}

__global__ __launch_bounds__(256)
void kv_final(const float* __restrict__ part, float* __restrict__ KVg, float* __restrict__ Ksum) {
    const int bh = blockIdx.x, tid = threadIdx.x;
    for (int idx = tid; idx < 1056; idx += 256) {
        float s = 0.f;
        for (int c = 0; c < 75; ++c) s += part[((long)(c * 32 + bh)) * 1056 + idx];
        if (idx < 1024) KVg[bh * 1024 + idx] = s;
        else Ksum[bh * 32 + idx - 1024] = s;
    }
}

// ---------------- attn message: msg = (Qf @ KV) * Z ----------------
__global__ __launch_bounds__(256)
void attn_msg(const uint16_t* __restrict__ qb, const float* __restrict__ KVg,
              const float* __restrict__ Ksum, uint16_t* __restrict__ msgout) {
    __shared__ float kv_sm[8192];
    __shared__ float ks_sm[256];
    __shared__ float qf_sm[8][264];
    const int tid = threadIdx.x;
    const int b = blockIdx.y;
    const long l0 = (long)blockIdx.x * 64;
    for (int idx = tid; idx < 8192; idx += 256) kv_sm[idx] = KVg[b * 8192 + idx];
    ks_sm[tid] = Ksum[b * 256 + tid];
    __syncthreads();
    const int h = tid >> 5, vc = tid & 31;
    const int rr = tid >> 5, e8 = (tid & 31) * 8;
    for (int r0 = 0; r0 < 64; r0 += 8) {
        long rowg = (long)b * LL + l0 + r0 + rr;
        uint4 qv = *(const uint4*)(qb + rowg * 256 + e8);
        qf_sm[rr][e8 + 0] = elup1(bfbits2f(qv.x & 0xFFFFu));
        qf_sm[rr][e8 + 1] = elup1(bfbits2f(qv.x >> 16));
        qf_sm[rr][e8 + 2] = elup1(bfbits2f(qv.y & 0xFFFFu));
        qf_sm[rr][e8 + 3] = elup1(bfbits2f(qv.y >> 16));
        qf_sm[rr][e8 + 4] = elup1(bfbits2f(qv.z & 0xFFFFu));
        qf_sm[rr][e8 + 5] = elup1(bfbits2f(qv.z >> 16));
        qf_sm[rr][e8 + 6] = elup1(bfbits2f(qv.w & 0xFFFFu));
        qf_sm[rr][e8 + 7] = elup1(bfbits2f(qv.w >> 16));
        __syncthreads();
        for (int r2 = 0; r2 < 8; ++r2) {
            float p = qf_sm[r2][h * 32 + vc] * ks_sm[h * 32 + vc];
#pragma unroll
            for (int m = 1; m < 32; m <<= 1) p += __shfl_xor(p, m, 64);
            float Z = 1.f / (p + 1e-6f);
            float acc = 0.f;
#pragma unroll
            for (int dd = 0; dd < 32; ++dd)
                acc += qf_sm[r2][h * 32 + dd] * kv_sm[(h * 32 + dd) * 32 + vc];
            long orow = (long)b * LL + l0 + r0 + r2;
            msgout[orow * 256 + tid] = f2bf(acc * Z);
        }
        __syncthreads();
    }
}

// ---------------- conv branch: f9 1x1 projection (24 -> 9 per (l, d')) ----------------
__global__ __launch_bounds__(256)
void f9_kernel(const uint16_t* __restrict__ qb, const uint16_t* __restrict__ kb,
               const uint16_t* __restrict__ vb, const float* __restrict__ fcw,
               const float* __restrict__ fcb, uint16_t* __restrict__ fconv) {
    __shared__ __align__(16) uint16_t sm[3][32][264];
    __shared__ float fw[9][24];
    __shared__ float fb[9];
    const int tid = threadIdx.x;
    const int b = blockIdx.y;
    const int l0 = blockIdx.x * 32;
    if (tid < 216) fw[tid / 24][tid % 24] = fcw[tid];
    if (tid >= 216 && tid < 225) fb[tid - 216] = fcb[tid - 216];
    for (int idx = tid; idx < 3072; idx += 256) {
        int tsr = idx >> 10, rem = idx & 1023, row = rem >> 5, c8 = (rem & 31) * 8;
        const uint16_t* src = tsr == 0 ? qb : (tsr == 1 ? kb : vb);
        *(uint4*)&sm[tsr][row][c8] = *(const uint4*)(src + ((long)(b * LL + l0 + row)) * 256 + c8);
    }
    __syncthreads();
    for (int idx = tid; idx < 9216; idx += 256) {
        int ch = idx >> 5, li = idx & 31;
        int dp = ch / 9, o = ch - dp * 9;
        float acc = fb[o];
#pragma unroll
        for (int hd = 0; hd < 8; ++hd) {
            int cb = hd * 32 + dp;
            acc += fw[o][3 * hd + 0] * bf2f(sm[0][li][cb]);
            acc += fw[o][3 * hd + 1] * bf2f(sm[1][li][cb]);
            acc += fw[o][3 * hd + 2] * bf2f(sm[2][li][cb]);
        }
        fconv[((long)(b * 288 + ch)) * LL + l0 + li] = f2bf(acc);
    }
}

// ---------------- depthwise-grouped 3x3 conv, register-tiled ----------------
// block: 256 thr = 8 xc(4 cols) x 8 m x 4 ys(6 rows); tile 32x24 per (b,g)
// LDS: halo tile [9][26][48] bf16 (col c == global x0-8+c; interior at c=8)
__global__ __launch_bounds__(256)
void dwconv2(const uint16_t* __restrict__ fconv, const float* __restrict__ depw,
             const float* __restrict__ depb, uint16_t* __restrict__ convout) {
    __shared__ __align__(16) uint16_t in_sm[9][26][48];
    __shared__ float w_sm[8][81];
    __shared__ float b_sm2[8];
    const int tid = threadIdx.x;
    const int bg = blockIdx.z, b = bg >> 5, g = bg & 31;
    const int y0 = blockIdx.y * 24;
    const int x0 = blockIdx.x * 32;
    for (int idx = tid; idx < 648; idx += 256)
        w_sm[idx / 81][idx % 81] = depw[(long)(g * 8) * 81 + idx];
    if (tid < 8) b_sm2[tid] = depb[g * 8 + tid];
    // stage 9 ch x 26 rows (y0-1 .. y0+24), cols x0-1 .. x0+32
    for (int rIdx = tid; rIdx < 234; rIdx += 256) {
        int i = rIdx / 26, r = rIdx - i * 26;
        int yy = y0 + r - 1;
        uint16_t* dst = &in_sm[i][r][0];
        if (yy >= 0 && yy < HH) {
            const uint16_t* rp = fconv + ((long)(b * 288 + g * 9 + i)) * LL + yy * WW;
            *(uint4*)&dst[8]  = *(const uint4*)(rp + x0);
            *(uint4*)&dst[16] = *(const uint4*)(rp + x0 + 8);
            *(uint4*)&dst[24] = *(const uint4*)(rp + x0 + 16);
            *(uint4*)&dst[32] = *(const uint4*)(rp + x0 + 24);
            dst[7]  = (x0 > 0) ? rp[x0 - 1] : (uint16_t)0;
            dst[40] = (x0 + 32 < WW) ? rp[x0 + 32] : (uint16_t)0;
        } else {
            uint4 z = {0, 0, 0, 0};
            *(uint4*)&dst[8] = z; *(uint4*)&dst[16] = z;
            *(uint4*)&dst[24] = z; *(uint4*)&dst[32] = z;
            dst[7] = 0; dst[40] = 0;
        }
    }
    __syncthreads();
    const int xc = tid & 7, m = (tid >> 3) & 7, ys = tid >> 6;
    float acc[6][4];
    float bias = b_sm2[m];
#pragma unroll
    for (int r = 0; r < 6; ++r)
#pragma unroll
        for (int o = 0; o < 4; ++o) acc[r][o] = bias;
    for (int i = 0; i < 9; ++i) {
        float w[9];
#pragma unroll
        for (int t = 0; t < 9; ++t) w[t] = w_sm[m][i * 9 + t];
#pragma unroll
        for (int rr = 0; rr < 8; ++rr) {
            const uint16_t* rowb = &in_sm[i][ys * 6 + rr][4 + xc * 4];
            uint2 lo = *(const uint2*)rowb;           // c4..c7
            uint2 hi = *(const uint2*)(rowb + 4);     // c8..c11
            uint32_t ex = *(const uint32_t*)(rowb + 8); // c12..c13
            float f[6];
            f[0] = bfbits2f(lo.y >> 16);
            f[1] = bfbits2f(hi.x & 0xFFFFu);
            f[2] = bfbits2f(hi.x >> 16);
            f[3] = bfbits2f(hi.y & 0xFFFFu);
            f[4] = bfbits2f(hi.y >> 16);
            f[5] = bfbits2f(ex & 0xFFFFu);
#pragma unroll
            for (int ky = 0; ky < 3; ++ky) {
                int ro = rr - ky;
                if (ro >= 0 && ro < 6) {
#pragma unroll
                    for (int o = 0; o < 4; ++o)
                        acc[ro][o] += w[ky * 3 + 0] * f[o] + w[ky * 3 + 1] * f[o + 1] + w[ky * 3 + 2] * f[o + 2];
                }
            }
        }
    }
    long chbase = ((long)(b * 256 + g * 8 + m)) * LL;
#pragma unroll
    for (int rl = 0; rl < 6; ++rl) {
        int y = y0 + ys * 6 + rl;
        uint2 st;
        st.x = pk2(f2bf(acc[rl][0]), f2bf(acc[rl][1]));
        st.y = pk2(f2bf(acc[rl][2]), f2bf(acc[rl][3]));
        *(uint2*)(convout + chbase + (long)y * WW + x0 + xc * 4) = st;
    }
}

// ---------------- launcher ----------------
extern "C" void kernel_launch(void* const* d_in, const int* in_sizes, int n_in,
                              void* d_out, int out_size, void* d_ws, size_t ws_size,
                              hipStream_t stream) {
    (void)in_sizes; (void)n_in; (void)out_size; (void)ws_size;
    const float* x      = (const float*)d_in[0];
    const float* src    = (const float*)d_in[1];
    const float* Wq     = (const float*)d_in[2];
    const float* Wk     = (const float*)d_in[3];
    const float* Wv     = (const float*)d_in[4];
    const float* Wmerge = (const float*)d_in[5];
    const float* Wmlp1  = (const float*)d_in[6];
    const float* Wmlp2  = (const float*)d_in[7];
    const float* ln1w   = (const float*)d_in[8];
    const float* ln1b   = (const float*)d_in[9];
    const float* ln2w   = (const float*)d_in[10];
    const float* ln2b   = (const float*)d_in[11];
    const float* Wdown  = (const float*)d_in[12];
    const float* Wup    = (const float*)d_in[13];
    const float* fcw    = (const float*)d_in[14];
    const float* fcb    = (const float*)d_in[15];
    const float* depw   = (const float*)d_in[16];
    const float* depb   = (const float*)d_in[17];
    const float* rate   = (const float*)d_in[18];

    char* ws = (char*)d_ws;
    const size_t SZ_NB = (size_t)NROWS * 256 * 2;
    const size_t O_Q = 0;
    const size_t O_K = SZ_NB;
    const size_t O_V = 2 * SZ_NB;
    const size_t O_FCONV = 3 * SZ_NB;
    const size_t O_CONVOUT = O_FCONV + (size_t)NBATCH * 288 * LL * 2;
    const size_t O_PART = O_CONVOUT + SZ_NB;
    const size_t O_KV = O_PART + (size_t)75 * 32 * 1056 * 4;
    const size_t O_KS = O_KV + (size_t)32 * 1024 * 4;
    const size_t O_WT = O_KS + (size_t)32 * 32 * 4;

    uint16_t* qB      = (uint16_t*)(ws + O_Q);
    uint16_t* kB      = (uint16_t*)(ws + O_K);
    uint16_t* vB      = (uint16_t*)(ws + O_V);
    uint16_t* fconv   = (uint16_t*)(ws + O_FCONV);
    uint16_t* convout = (uint16_t*)(ws + O_CONVOUT);
    float*    part    = (float*)(ws + O_PART);
    float*    KVg     = (float*)(ws + O_KV);
    float*    Ksg     = (float*)(ws + O_KS);
    uint16_t* wt_q    = (uint16_t*)(ws + O_WT);
    uint16_t* wt_k    = wt_q + 256 * 256;
    uint16_t* wt_v    = wt_k + 256 * 256;
    uint16_t* wt_m    = wt_v + 256 * 256;
    uint16_t* wt_m1   = wt_m + 256 * 256;
    uint16_t* wt_m2   = wt_m1 + 512 * 512;
    uint16_t* wt_d    = wt_m2 + 512 * 256;
    uint16_t* wt_u    = wt_d + 512 * 64;
    // aliases (lifetimes vs launch order):
    uint16_t* msgattn = kB;                       // attn_msg output (k dead after f9/kv)
    uint16_t* msgB    = vB;                       // LN1 out over v
    uint16_t* hidden  = qB;                       // MLP hidden (N x 512) over q+k
    uint16_t* msg2    = fconv;                    // LN2 out over f_conv
    uint16_t* h2      = (uint16_t*)(ws + O_PART); // adapter hidden over partials

    prep_wt<<<256, 256, 0, stream>>>(Wq, wt_q, 256, 256);
    prep_wt<<<256, 256, 0, stream>>>(Wk, wt_k, 256, 256);
    prep_wt<<<256, 256, 0, stream>>>(Wv, wt_v, 256, 256);
    prep_wt<<<256, 256, 0, stream>>>(Wmerge, wt_m, 256, 256);
    prep_wt<<<1024, 256, 0, stream>>>(Wmlp1, wt_m1, 512, 512);
    prep_wt<<<512, 256, 0, stream>>>(Wmlp2, wt_m2, 512, 256);
    prep_wt<<<128, 256, 0, stream>>>(Wdown, wt_d, 512, 64);
    prep_wt<<<64, 256, 0, stream>>>(Wup, wt_u, 64, 256);

    const dim3 g600(NROWS / 128, 1);
    // --- QKV ---
    gemm_big<256, 1, EPI_NONE><<<g600, 512, 0, stream>>>(x, nullptr, nullptr, wt_q, 256, qB, nullptr, 256,
        nullptr, nullptr, nullptr, nullptr, nullptr, nullptr);
    gemm_big<256, 1, EPI_NONE><<<g600, 512, 0, stream>>>(src, nullptr, nullptr, wt_k, 256, kB, nullptr, 256,
        nullptr, nullptr, nullptr, nullptr, nullptr, nullptr);
    gemm_big<256, 1, EPI_NONE><<<g600, 512, 0, stream>>>(src, nullptr, nullptr, wt_v, 256, vB, nullptr, 256,
        nullptr, nullptr, nullptr, nullptr, nullptr, nullptr);
    // --- linear attention KV reduce ---
    kv_partial<<<dim3(75, 32), 256, 0, stream>>>(kB, vB, part);
    kv_final<<<32, 256, 0, stream>>>(part, KVg, Ksg);
    // --- conv branch ---
    f9_kernel<<<dim3(LL / 32, NBATCH), 256, 0, stream>>>(qB, kB, vB, fcw, fcb, fconv);
    dwconv2<<<dim3(5, 5, 128), 256, 0, stream>>>(fconv, depw, depb, convout);
    // --- attention message ---
    attn_msg<<<dim3(LL / 64, NBATCH), 256, 0, stream>>>(qB, KVg, Ksg, msgattn);
    // --- merge + LN1 ---
    gemm_big<256, 0, EPI_LN><<<g600, 512, 0, stream>>>(nullptr, msgattn, nullptr, wt_m, 256, msgB, nullptr, 256,
        ln1w, ln1b, nullptr, nullptr, nullptr, nullptr);
    // --- MLP1 + relu ---
    gemm_big<256, 2, EPI_RELU><<<dim3(NROWS / 128, 2), 512, 0, stream>>>(x, nullptr, msgB, wt_m1, 512, hidden, nullptr, 512,
        nullptr, nullptr, nullptr, nullptr, nullptr, nullptr);
    // --- MLP2 + LN2 ---
    gemm_big<256, 0, EPI_LN><<<g600, 512, 0, stream>>>(nullptr, hidden, nullptr, wt_m2, 512, msg2, nullptr, 256,
        ln2w, ln2b, nullptr, nullptr, nullptr, nullptr);
    // --- adapter down + relu ---
    gemm_big<64, 2, EPI_RELU><<<g600, 512, 0, stream>>>(x, nullptr, msg2, wt_d, 512, h2, nullptr, 64,
        nullptr, nullptr, nullptr, nullptr, nullptr, nullptr);
    // --- adapter up + final combine ---
    gemm_big<256, 0, EPI_FINAL><<<g600, 512, 0, stream>>>(nullptr, h2, nullptr, wt_u, 64, nullptr, (float*)d_out, 256,
        nullptr, nullptr, x, msg2, convout, rate);
}

// Round 3
// 835.279 us; speedup vs baseline: 1.5442x; 1.1455x over previous
//
// LoFTR encoder layer — MI355X / gfx950. Round 3: f9 XOR-swizzle rewrite,
// MFMA linear-attention message, kv_partial float4, all-bf16 GEMM staging
// (Q/K GEMMs emit bf16 copies of x/src as side-outputs), fused weight prep.
#include <hip/hip_runtime.h>
#include <stdint.h>

#define LL 19200
#define NBATCH 4
#define NROWS (NBATCH * LL)   // 76800
#define HH 120
#define WW 160

typedef short bhalf8 __attribute__((ext_vector_type(8)));
typedef float f32x4 __attribute__((ext_vector_type(4)));

__device__ __forceinline__ float bfbits2f(uint32_t u) { union { uint32_t i; float f; } c; c.i = u << 16; return c.f; }
__device__ __forceinline__ float bf2f(uint16_t h) { return bfbits2f((uint32_t)h); }
__device__ __forceinline__ uint16_t f2bf(float f) {
    union { float f; uint32_t i; } c; c.f = f;
    return (uint16_t)((c.i + 0x7FFFu + ((c.i >> 16) & 1u)) >> 16);
}
__device__ __forceinline__ uint32_t pk2(uint16_t a, uint16_t b) { return (uint32_t)a | ((uint32_t)b << 16); }
__device__ __forceinline__ float elup1(float x) { return x > 0.f ? x + 1.f : expf(x); } // elu(x)+1

__device__ __forceinline__ uint4 pack8f(const float* p) {
    float4 lo = *(const float4*)p; float4 hi = *(const float4*)(p + 4);
    uint4 s;
    s.x = pk2(f2bf(lo.x), f2bf(lo.y)); s.y = pk2(f2bf(lo.z), f2bf(lo.w));
    s.z = pk2(f2bf(hi.x), f2bf(hi.y)); s.w = pk2(f2bf(hi.z), f2bf(hi.w));
    return s;
}

// async global->LDS, 16B per lane; lds dst is wave-uniform base (lane*16 added by HW)
__device__ __forceinline__ void gll16(const void* g, void* l) {
    __builtin_amdgcn_global_load_lds((const __attribute__((address_space(1))) uint32_t*)g,
                                     (__attribute__((address_space(3))) uint32_t*)l, 16, 0, 0);
}

// ---------------- fused weight transpose to bf16 [out][in] ----------------
__global__ __launch_bounds__(256)
void prep_all(const float* __restrict__ Wq, const float* __restrict__ Wk,
              const float* __restrict__ Wv, const float* __restrict__ Wm,
              const float* __restrict__ Wm1, const float* __restrict__ Wm2,
              const float* __restrict__ Wd, const float* __restrict__ Wu,
              uint16_t* __restrict__ wq, uint16_t* __restrict__ wk,
              uint16_t* __restrict__ wvv, uint16_t* __restrict__ wm,
              uint16_t* __restrict__ wm1, uint16_t* __restrict__ wm2,
              uint16_t* __restrict__ wd, uint16_t* __restrict__ wu) {
    int blk = blockIdx.x;
    const float* s; uint16_t* d; int K, N, base;
    if (blk < 1024) {
        int which = blk >> 8; base = which << 8;
        s = which == 0 ? Wq : which == 1 ? Wk : which == 2 ? Wv : Wm;
        d = which == 0 ? wq : which == 1 ? wk : which == 2 ? wvv : wm;
        K = 256; N = 256;
    } else if (blk < 2048) { s = Wm1; d = wm1; K = 512; N = 512; base = 1024; }
    else if (blk < 2560)   { s = Wm2; d = wm2; K = 512; N = 256; base = 2048; }
    else if (blk < 2688)   { s = Wd;  d = wd;  K = 512; N = 64;  base = 2560; }
    else                   { s = Wu;  d = wu;  K = 64;  N = 256; base = 2688; }
    int idx = (blk - base) * 256 + threadIdx.x;
    int n = idx / K, kk = idx - n * K;
    d[idx] = f2bf(s[(long)kk * N + n]);
}

// ---------------- 128xBN MFMA GEMM, 512 threads, 8 waves ----------------
// MODE_A: 0 = bf16 A0b stride K; 1 = f32 A0f stride K (optional bf16 sideout);
//         2 = concat f32 A0f(256) | bf16 A1b(256); 3 = concat bf16 A0b | bf16 A1b
#define EPI_NONE 0
#define EPI_RELU 1
#define EPI_LN 2
#define EPI_FINAL 3

template<int BN, int MODE_A, int EPI>
__global__ __launch_bounds__(512)
void gemm_big(const float* __restrict__ A0f, const uint16_t* __restrict__ A0b,
              const uint16_t* __restrict__ A1b,
              const uint16_t* __restrict__ Wt, int K,
              uint16_t* __restrict__ outb, float* __restrict__ outf, int outW,
              uint16_t* __restrict__ sideout,
              const float* __restrict__ lnw, const float* __restrict__ lnb,
              const float* __restrict__ xres, const uint16_t* __restrict__ xresb,
              const uint16_t* __restrict__ msg2res,
              const uint16_t* __restrict__ convres, const float* __restrict__ ratep)
{
    constexpr int WCOLS = BN / 64;            // 4 (BN=256) or 1 (BN=64)
    constexpr int WROWS = 8 / WCOLS;          // 2 or 8
    constexpr int MT = 128 / (WROWS * 16);    // 4 or 1
    __shared__ __align__(16) uint16_t a_sm[128 * 32];
    __shared__ __align__(16) uint16_t b_sm[BN * 32];
    const int tid = threadIdx.x;
    const int lane = tid & 63;
    const int wv = tid >> 6;
    const int wr = wv / WCOLS, wc = wv % WCOLS;
    const long row0 = (long)blockIdx.x * 128;
    const int col0 = blockIdx.y * BN;

    f32x4 acc[MT][4];
#pragma unroll
    for (int m = 0; m < MT; ++m)
#pragma unroll
        for (int n = 0; n < 4; ++n) acc[m][n] = (f32x4){0.f, 0.f, 0.f, 0.f};

    const int sr = tid >> 2;          // 0..127
    const int sc = (tid & 3) * 8;     // 0,8,16,24
    const long argA = row0 + sr;
    uint16_t* a_dst = a_sm + wv * 512;
    uint16_t* b_dst = b_sm + wv * 512;

    for (int k0 = 0; k0 < K; k0 += 32) {
        // ---- stage A (128x32 bf16) ----
        if (MODE_A == 0) {
            gll16(A0b + argA * (long)K + k0 + sc, a_dst);
        } else if (MODE_A == 1) {
            uint4 stg = pack8f(A0f + argA * (long)K + k0 + sc);
            *(uint4*)&a_sm[sr * 32 + sc] = stg;
            if (sideout) *(uint4*)(sideout + argA * (long)K + k0 + sc) = stg;
        } else if (MODE_A == 2) {
            if (k0 < 256) *(uint4*)&a_sm[sr * 32 + sc] = pack8f(A0f + argA * 256 + k0 + sc);
            else          gll16(A1b + argA * 256 + (k0 - 256) + sc, a_dst);
        } else {
            const uint16_t* srcp = (k0 < 256) ? (A0b + argA * 256 + k0 + sc)
                                              : (A1b + argA * 256 + (k0 - 256) + sc);
            gll16(srcp, a_dst);
        }
        // ---- stage B (BNx32 bf16) ----
        if (BN == 256) {
            gll16(Wt + (long)(col0 + sr) * K + k0 + sc, b_dst);
            gll16(Wt + (long)(col0 + 128 + sr) * K + k0 + sc, b_sm + 4096 + wv * 512);
        } else {
            if (tid < 256) gll16(Wt + (long)(col0 + sr) * K + k0 + sc, b_dst);
        }
        __syncthreads();
        bhalf8 af[MT];
#pragma unroll
        for (int m = 0; m < MT; ++m)
            af[m] = *(const bhalf8*)&a_sm[(wr * MT * 16 + m * 16 + (lane & 15)) * 32 + (lane >> 4) * 8];
#pragma unroll
        for (int n = 0; n < 4; ++n) {
            bhalf8 bfr = *(const bhalf8*)&b_sm[(wc * 64 + n * 16 + (lane & 15)) * 32 + (lane >> 4) * 8];
#pragma unroll
            for (int m = 0; m < MT; ++m)
                acc[m][n] = __builtin_amdgcn_mfma_f32_16x16x32_bf16(af[m], bfr, acc[m][n], 0, 0, 0);
        }
        __syncthreads();
    }

    const int cl = lane & 15;
    const int rg4 = (lane >> 4) * 4;

    if constexpr (EPI == EPI_LN) {
        __shared__ float red_s[4][128];
        __shared__ float red_ss[4][128];
#pragma unroll
        for (int m = 0; m < MT; ++m)
#pragma unroll
            for (int j = 0; j < 4; ++j) {
                float p = 0.f, pp = 0.f;
#pragma unroll
                for (int n = 0; n < 4; ++n) { float v = acc[m][n][j]; p += v; pp += v * v; }
#pragma unroll
                for (int msk = 1; msk < 16; msk <<= 1) { p += __shfl_xor(p, msk, 64); pp += __shfl_xor(pp, msk, 64); }
                if (cl == 0) {
                    int lr = wr * 64 + m * 16 + rg4 + j;
                    red_s[wc][lr] = p; red_ss[wc][lr] = pp;
                }
            }
        __syncthreads();
#pragma unroll
        for (int m = 0; m < MT; ++m)
#pragma unroll
            for (int j = 0; j < 4; ++j) {
                int lr = wr * 64 + m * 16 + rg4 + j;
                float s = red_s[0][lr] + red_s[1][lr] + red_s[2][lr] + red_s[3][lr];
                float ss = red_ss[0][lr] + red_ss[1][lr] + red_ss[2][lr] + red_ss[3][lr];
                float mu = s * (1.f / 256.f);
                float var = ss * (1.f / 256.f) - mu * mu;
                float rstd = rsqrtf(var + 1e-5f);
                long rowg = row0 + lr;
#pragma unroll
                for (int n = 0; n < 4; ++n) {
                    int col = wc * 64 + n * 16 + cl;
                    float vv = (acc[m][n][j] - mu) * rstd * lnw[col] + lnb[col];
                    outb[rowg * (long)outW + col] = f2bf(vv);
                }
            }
    } else if constexpr (EPI == EPI_FINAL) {
        float rate = ratep[0];
#pragma unroll
        for (int m = 0; m < MT; ++m)
#pragma unroll
            for (int j = 0; j < 4; ++j) {
                long rowg = row0 + wr * MT * 16 + m * 16 + rg4 + j;
                int bb = (int)(rowg / LL);
                int ll = (int)(rowg - (long)bb * LL);
#pragma unroll
                for (int n = 0; n < 4; ++n) {
                    int col = wc * 64 + n * 16 + cl;
                    long o = rowg * 256 + col;
                    float xv = xresb ? bf2f(xresb[o]) : xres[o];
                    float m2 = bf2f(msg2res[o]);
                    float cv = bf2f(convres[((long)(bb * 256 + col)) * LL + ll]);
                    outf[o] = xv + m2 + 0.1f * acc[m][n][j] + rate * cv;
                }
            }
    } else {
#pragma unroll
        for (int m = 0; m < MT; ++m)
#pragma unroll
            for (int j = 0; j < 4; ++j) {
                long rowg = row0 + wr * MT * 16 + m * 16 + rg4 + j;
#pragma unroll
                for (int n = 0; n < 4; ++n) {
                    int col = col0 + wc * 64 + n * 16 + cl;
                    float vv = acc[m][n][j];
                    if (EPI == EPI_RELU) vv = vv > 0.f ? vv : 0.f;
                    outb[rowg * (long)outW + col] = f2bf(vv);
                }
            }
    }
}

// ---------------- linear attention: stage 1 partial KV / Ksum ----------------
__global__ __launch_bounds__(256)
void kv_partial(const uint16_t* __restrict__ kb, const uint16_t* __restrict__ vb,
                float* __restrict__ part) {
    __shared__ float kf_sm[32][33];
    __shared__ float v_sm[32][36];   // 36-pad: 16B-aligned rows, float4-readable
    const int tid = threadIdx.x;
    const int bh = blockIdx.y, b = bh >> 3, h = bh & 7;
    const int s0 = blockIdx.x * 256;
    const int d = tid >> 3, vg = tid & 7;
    const int sl = tid >> 3, e4 = (tid & 7) * 4;
    float a0 = 0.f, a1 = 0.f, a2 = 0.f, a3 = 0.f, aKs = 0.f;
    for (int it = 0; it < 8; ++it) {
        long base = ((long)(b * LL + s0 + it * 32 + sl)) * 256 + h * 32 + e4;
        uint2 kk = *(const uint2*)(kb + base);
        uint2 vv = *(const uint2*)(vb + base);
        kf_sm[sl][e4 + 0] = elup1(bfbits2f(kk.x & 0xFFFFu));
        kf_sm[sl][e4 + 1] = elup1(bfbits2f(kk.x >> 16));
        kf_sm[sl][e4 + 2] = elup1(bfbits2f(kk.y & 0xFFFFu));
        kf_sm[sl][e4 + 3] = elup1(bfbits2f(kk.y >> 16));
        float4 vf;
        vf.x = bfbits2f(vv.x & 0xFFFFu); vf.y = bfbits2f(vv.x >> 16);
        vf.z = bfbits2f(vv.y & 0xFFFFu); vf.w = bfbits2f(vv.y >> 16);
        *(float4*)&v_sm[sl][e4] = vf;
        __syncthreads();
#pragma unroll 8
        for (int s = 0; s < 32; ++s) {
            float kf = kf_sm[s][d];
            aKs += kf;
            float4 v4 = *(const float4*)&v_sm[s][vg * 4];
            a0 += kf * v4.x; a1 += kf * v4.y; a2 += kf * v4.z; a3 += kf * v4.w;
        }
        __syncthreads();
    }
    long pb = ((long)(blockIdx.x * 32 + bh)) * 1056;
    part[pb + d * 32 + vg * 4 + 0] = a0;
    part[pb + d * 32 + vg * 4 + 1] = a1;
    part[pb + d * 32 + vg * 4 + 2] = a2;
    part[pb + d * 32 + vg * 4 + 3] = a3;
    if (vg == 0) part[pb + 1024 + d] = aKs;
}

__global__ __launch_bounds__(256)
void kv_final(const float* __restrict__ part, float* __restrict__ KVg, float* __restrict__ Ksum) {
    const int bh = blockIdx.x, tid = threadIdx.x;
    for (int idx = tid; idx < 1056; idx += 256) {
        float s = 0.f;
        for (int c = 0; c < 75; ++c) s += part[((long)(c * 32 + bh)) * 1056 + idx];
        if (idx < 1024) KVg[bh * 1024 + idx] = s;
        else Ksum[bh * 32 + idx - 1024] = s;
    }
}

// ---------------- attn message via MFMA: msg = (Qf @ KV_h) * Z ----------------
// block = 256 thr (4 waves) x 64 rows; wave w handles h = {2w, 2w+1}.
// A-frag: row=l&15, k=8*(l>>4)+i (Qf). B-frag: col=l&15, k=8*(l>>4)+i (KV).
// D: col=l&15, row=(l>>4)*4+j. Z-dot fused via A-frag partials + shfl_xor(16,32).
__global__ __launch_bounds__(256)
void attn_mfma(const uint16_t* __restrict__ qb, const float* __restrict__ KVg,
               const float* __restrict__ Ksum, uint16_t* __restrict__ msgout) {
    const int tid = threadIdx.x;
    const int lane = tid & 63;
    const int wv = tid >> 6;
    const long l0 = (long)blockIdx.x * 64;
    const int b = (int)(l0 / LL);            // 64 | 19200, blocks never straddle batch
    const int l15 = lane & 15, lk = lane >> 4;
#pragma unroll
    for (int hi = 0; hi < 2; ++hi) {
        const int h = wv * 2 + hi;
        const float* kvb = KVg + ((long)(b * 8 + h)) * 1024;
        const float* ksb = Ksum + (b * 8 + h) * 32;
        bhalf8 B0, B1;
        float ks[8];
#pragma unroll
        for (int i = 0; i < 8; ++i) {
            int k = lk * 8 + i;
            B0[i] = (short)f2bf(kvb[k * 32 + l15]);
            B1[i] = (short)f2bf(kvb[k * 32 + 16 + l15]);
            ks[i] = ksb[k];
        }
#pragma unroll
        for (int rt = 0; rt < 4; ++rt) {
            long row = l0 + rt * 16 + l15;
            uint4 qv = *(const uint4*)(qb + row * 256 + h * 32 + lk * 8);
            float qf[8];
            qf[0] = elup1(bfbits2f(qv.x & 0xFFFFu)); qf[1] = elup1(bfbits2f(qv.x >> 16));
            qf[2] = elup1(bfbits2f(qv.y & 0xFFFFu)); qf[3] = elup1(bfbits2f(qv.y >> 16));
            qf[4] = elup1(bfbits2f(qv.z & 0xFFFFu)); qf[5] = elup1(bfbits2f(qv.z >> 16));
            qf[6] = elup1(bfbits2f(qv.w & 0xFFFFu)); qf[7] = elup1(bfbits2f(qv.w >> 16));
            bhalf8 A;
#pragma unroll
            for (int i = 0; i < 8; ++i) A[i] = (short)f2bf(qf[i]);
            float p = qf[0]*ks[0] + qf[1]*ks[1] + qf[2]*ks[2] + qf[3]*ks[3]
                    + qf[4]*ks[4] + qf[5]*ks[5] + qf[6]*ks[6] + qf[7]*ks[7];
            p += __shfl_xor(p, 16, 64);
            p += __shfl_xor(p, 32, 64);     // z-dot for row (l0+rt*16+l15), dup over lk
            f32x4 d0 = (f32x4){0.f,0.f,0.f,0.f}, d1 = (f32x4){0.f,0.f,0.f,0.f};
            d0 = __builtin_amdgcn_mfma_f32_16x16x32_bf16(A, B0, d0, 0, 0, 0);
            d1 = __builtin_amdgcn_mfma_f32_16x16x32_bf16(A, B1, d1, 0, 0, 0);
#pragma unroll
            for (int j = 0; j < 4; ++j) {
                int orl = lk * 4 + j;
                float zr = __shfl(p, orl, 64);       // lane orl (<16) holds that row's dot
                float Z = 1.f / (zr + 1e-6f);
                long orow = l0 + rt * 16 + orl;
                msgout[orow * 256 + h * 32 + l15]      = f2bf(d0[j] * Z);
                msgout[orow * 256 + h * 32 + 16 + l15] = f2bf(d1[j] * Z);
            }
        }
    }
}

// ---------------- conv branch: f9 1x1 projection (24 -> 9 per (l, d')) ----------------
// LDS [3][32][256] bf16, 16B-granule XOR swizzle (phys = logical ^ ((row&7)<<4)).
// Thread (li, g): 4 d's (g*4..+3); 24 ds_read_b64; weights via uniform s_loads.
__global__ __launch_bounds__(256)
void f9_kernel(const uint16_t* __restrict__ qb, const uint16_t* __restrict__ kb,
               const uint16_t* __restrict__ vb, const float* __restrict__ fcw,
               const float* __restrict__ fcb, uint16_t* __restrict__ fconv) {
    __shared__ __align__(16) uint16_t sm[3 * 32 * 256];
    char* smb = (char*)sm;
    const int tid = threadIdx.x;
    const int b = blockIdx.y;
    const int l0 = blockIdx.x * 32;
    // stage q/k/v rows with XOR-swizzled 16B chunks
    for (int idx = tid; idx < 3072; idx += 256) {
        int tsr = idx >> 10, row = (idx >> 5) & 31, c = idx & 31;
        const uint16_t* src = tsr == 0 ? qb : (tsr == 1 ? kb : vb);
        uint4 v = *(const uint4*)(src + ((long)(b * LL + l0 + row)) * 256 + c * 8);
        int boff = (c * 16) ^ ((row & 7) << 4);
        *(uint4*)(smb + (tsr * 32 + row) * 512 + boff) = v;
    }
    __syncthreads();
    const int li = tid & 31, g = tid >> 5;
    float acc[9][4];
#pragma unroll
    for (int o = 0; o < 9; ++o) {
        float bv = fcb[o];
#pragma unroll
        for (int j = 0; j < 4; ++j) acc[o][j] = bv;
    }
    const int swz = (li & 7) << 4;
#pragma unroll
    for (int h = 0; h < 8; ++h) {
        float f[3][4];
#pragma unroll
        for (int s = 0; s < 3; ++s) {
            int boff = (h * 64 + g * 8) ^ swz;
            uint2 r = *(const uint2*)(smb + (s * 32 + li) * 512 + boff);
            f[s][0] = bfbits2f(r.x & 0xFFFFu); f[s][1] = bfbits2f(r.x >> 16);
            f[s][2] = bfbits2f(r.y & 0xFFFFu); f[s][3] = bfbits2f(r.y >> 16);
        }
#pragma unroll
        for (int o = 0; o < 9; ++o) {
            float w0 = fcw[o * 24 + 3 * h + 0];
            float w1 = fcw[o * 24 + 3 * h + 1];
            float w2 = fcw[o * 24 + 3 * h + 2];
#pragma unroll
            for (int j = 0; j < 4; ++j)
                acc[o][j] += w0 * f[0][j] + w1 * f[1][j] + w2 * f[2][j];
        }
    }
    const long ob = (long)(b * 288) * LL + l0 + li;
#pragma unroll
    for (int j = 0; j < 4; ++j) {
        int dp = g * 4 + j;
#pragma unroll
        for (int o = 0; o < 9; ++o)
            fconv[ob + (long)(dp * 9 + o) * LL] = f2bf(acc[o][j]);
    }
}

// ---------------- depthwise-grouped 3x3 conv, register-tiled ----------------
__global__ __launch_bounds__(256)
void dwconv2(const uint16_t* __restrict__ fconv, const float* __restrict__ depw,
             const float* __restrict__ depb, uint16_t* __restrict__ convout) {
    __shared__ __align__(16) uint16_t in_sm[9][26][48];
    __shared__ float w_sm[8][81];
    __shared__ float b_sm2[8];
    const int tid = threadIdx.x;
    const int bg = blockIdx.z, b = bg >> 5, g = bg & 31;
    const int y0 = blockIdx.y * 24;
    const int x0 = blockIdx.x * 32;
    for (int idx = tid; idx < 648; idx += 256)
        w_sm[idx / 81][idx % 81] = depw[(long)(g * 8) * 81 + idx];
    if (tid < 8) b_sm2[tid] = depb[g * 8 + tid];
    for (int rIdx = tid; rIdx < 234; rIdx += 256) {
        int i = rIdx / 26, r = rIdx - i * 26;
        int yy = y0 + r - 1;
        uint16_t* dst = &in_sm[i][r][0];
        if (yy >= 0 && yy < HH) {
            const uint16_t* rp = fconv + ((long)(b * 288 + g * 9 + i)) * LL + yy * WW;
            *(uint4*)&dst[8]  = *(const uint4*)(rp + x0);
            *(uint4*)&dst[16] = *(const uint4*)(rp + x0 + 8);
            *(uint4*)&dst[24] = *(const uint4*)(rp + x0 + 16);
            *(uint4*)&dst[32] = *(const uint4*)(rp + x0 + 24);
            dst[7]  = (x0 > 0) ? rp[x0 - 1] : (uint16_t)0;
            dst[40] = (x0 + 32 < WW) ? rp[x0 + 32] : (uint16_t)0;
        } else {
            uint4 z = {0, 0, 0, 0};
            *(uint4*)&dst[8] = z; *(uint4*)&dst[16] = z;
            *(uint4*)&dst[24] = z; *(uint4*)&dst[32] = z;
            dst[7] = 0; dst[40] = 0;
        }
    }
    __syncthreads();
    const int xi = tid & 7, m = (tid >> 3) & 7, ys = tid >> 6;
    float acc[6][4];
    float bias = b_sm2[m];
#pragma unroll
    for (int r = 0; r < 6; ++r)
#pragma unroll
        for (int o = 0; o < 4; ++o) acc[r][o] = bias;
    for (int i = 0; i < 9; ++i) {
        float w[9];
#pragma unroll
        for (int t = 0; t < 9; ++t) w[t] = w_sm[m][i * 9 + t];
#pragma unroll
        for (int rr = 0; rr < 8; ++rr) {
            const uint16_t* rowb = &in_sm[i][ys * 6 + rr][4 + xi * 4];
            uint2 lo = *(const uint2*)rowb;
            uint2 hi = *(const uint2*)(rowb + 4);
            uint32_t ex = *(const uint32_t*)(rowb + 8);
            float f[6];
            f[0] = bfbits2f(lo.y >> 16);
            f[1] = bfbits2f(hi.x & 0xFFFFu);
            f[2] = bfbits2f(hi.x >> 16);
            f[3] = bfbits2f(hi.y & 0xFFFFu);
            f[4] = bfbits2f(hi.y >> 16);
            f[5] = bfbits2f(ex & 0xFFFFu);
#pragma unroll
            for (int ky = 0; ky < 3; ++ky) {
                int ro = rr - ky;
                if (ro >= 0 && ro < 6) {
#pragma unroll
                    for (int o = 0; o < 4; ++o)
                        acc[ro][o] += w[ky * 3 + 0] * f[o] + w[ky * 3 + 1] * f[o + 1] + w[ky * 3 + 2] * f[o + 2];
                }
            }
        }
    }
    long chbase = ((long)(b * 256 + g * 8 + m)) * LL;
#pragma unroll
    for (int rl = 0; rl < 6; ++rl) {
        int y = y0 + ys * 6 + rl;
        uint2 st;
        st.x = pk2(f2bf(acc[rl][0]), f2bf(acc[rl][1]));
        st.y = pk2(f2bf(acc[rl][2]), f2bf(acc[rl][3]));
        *(uint2*)(convout + chbase + (long)y * WW + x0 + xi * 4) = st;
    }
}

// ---------------- launcher ----------------
extern "C" void kernel_launch(void* const* d_in, const int* in_sizes, int n_in,
                              void* d_out, int out_size, void* d_ws, size_t ws_size,
                              hipStream_t stream) {
    (void)in_sizes; (void)n_in; (void)out_size;
    const float* x      = (const float*)d_in[0];
    const float* src    = (const float*)d_in[1];
    const float* Wq     = (const float*)d_in[2];
    const float* Wk     = (const float*)d_in[3];
    const float* Wv     = (const float*)d_in[4];
    const float* Wmerge = (const float*)d_in[5];
    const float* Wmlp1  = (const float*)d_in[6];
    const float* Wmlp2  = (const float*)d_in[7];
    const float* ln1w   = (const float*)d_in[8];
    const float* ln1b   = (const float*)d_in[9];
    const float* ln2w   = (const float*)d_in[10];
    const float* ln2b   = (const float*)d_in[11];
    const float* Wdown  = (const float*)d_in[12];
    const float* Wup    = (const float*)d_in[13];
    const float* fcw    = (const float*)d_in[14];
    const float* fcb    = (const float*)d_in[15];
    const float* depw   = (const float*)d_in[16];
    const float* depb   = (const float*)d_in[17];
    const float* rate   = (const float*)d_in[18];

    char* ws = (char*)d_ws;
    const size_t SZ_NB = (size_t)NROWS * 256 * 2;            // 39,321,600
    const size_t O_Q = 0;
    const size_t O_K = SZ_NB;
    const size_t O_V = 2 * SZ_NB;
    const size_t O_FCONV = 3 * SZ_NB;
    const size_t O_CONVOUT = O_FCONV + (size_t)NBATCH * 288 * LL * 2;
    const size_t O_PART = O_CONVOUT + SZ_NB;
    const size_t O_KV = O_PART + (size_t)75 * 32 * 1056 * 4;
    const size_t O_KS = O_KV + (size_t)32 * 1024 * 4;
    const size_t O_WT = O_KS + (size_t)32 * 32 * 4;
    const size_t O_XB = O_WT + 704512 * 2 + 1024;            // after weights (1.41MB), aligned
    const size_t O_SRCB = O_XB + SZ_NB;
    const size_t NEED = O_SRCB + SZ_NB;

    uint16_t* qB      = (uint16_t*)(ws + O_Q);
    uint16_t* kB      = (uint16_t*)(ws + O_K);
    uint16_t* vB      = (uint16_t*)(ws + O_V);
    uint16_t* fconv   = (uint16_t*)(ws + O_FCONV);
    uint16_t* convout = (uint16_t*)(ws + O_CONVOUT);
    float*    part    = (float*)(ws + O_PART);
    float*    KVg     = (float*)(ws + O_KV);
    float*    Ksg     = (float*)(ws + O_KS);
    uint16_t* wt_q    = (uint16_t*)(ws + O_WT);
    uint16_t* wt_k    = wt_q + 256 * 256;
    uint16_t* wt_v    = wt_k + 256 * 256;
    uint16_t* wt_m    = wt_v + 256 * 256;
    uint16_t* wt_m1   = wt_m + 256 * 256;
    uint16_t* wt_m2   = wt_m1 + 512 * 512;
    uint16_t* wt_d    = wt_m2 + 512 * 256;
    uint16_t* wt_u    = wt_d + 512 * 64;
    uint16_t* xb      = (uint16_t*)(ws + O_XB);
    uint16_t* srcb    = (uint16_t*)(ws + O_SRCB);
    // aliases (lifetimes vs launch order):
    uint16_t* msgattn = kB;                       // attn output (k dead after f9/kv)
    uint16_t* msgB    = vB;                       // LN1 out over v
    uint16_t* hidden  = qB;                       // MLP hidden (N x 512) over q+k
    uint16_t* msg2    = fconv;                    // LN2 out over f_conv
    uint16_t* h2      = (uint16_t*)(ws + O_PART); // adapter hidden over partials

    const bool big = ws_size >= NEED;

    prep_all<<<2752, 256, 0, stream>>>(Wq, Wk, Wv, Wmerge, Wmlp1, Wmlp2, Wdown, Wup,
                                       wt_q, wt_k, wt_v, wt_m, wt_m1, wt_m2, wt_d, wt_u);

    const dim3 g600(NROWS / 128, 1);
    // --- QKV (Q/K also emit bf16 copies of x/src when workspace allows) ---
    gemm_big<256, 1, EPI_NONE><<<g600, 512, 0, stream>>>(x, nullptr, nullptr, wt_q, 256, qB, nullptr, 256,
        big ? xb : nullptr, nullptr, nullptr, nullptr, nullptr, nullptr, nullptr, nullptr);
    gemm_big<256, 1, EPI_NONE><<<g600, 512, 0, stream>>>(src, nullptr, nullptr, wt_k, 256, kB, nullptr, 256,
        big ? srcb : nullptr, nullptr, nullptr, nullptr, nullptr, nullptr, nullptr, nullptr);
    if (big) {
        gemm_big<256, 0, EPI_NONE><<<g600, 512, 0, stream>>>(nullptr, srcb, nullptr, wt_v, 256, vB, nullptr, 256,
            nullptr, nullptr, nullptr, nullptr, nullptr, nullptr, nullptr, nullptr);
    } else {
        gemm_big<256, 1, EPI_NONE><<<g600, 512, 0, stream>>>(src, nullptr, nullptr, wt_v, 256, vB, nullptr, 256,
            nullptr, nullptr, nullptr, nullptr, nullptr, nullptr, nullptr, nullptr);
    }
    // --- linear attention KV reduce ---
    kv_partial<<<dim3(75, 32), 256, 0, stream>>>(kB, vB, part);
    kv_final<<<32, 256, 0, stream>>>(part, KVg, Ksg);
    // --- conv branch ---
    f9_kernel<<<dim3(LL / 32, NBATCH), 256, 0, stream>>>(qB, kB, vB, fcw, fcb, fconv);
    dwconv2<<<dim3(5, 5, 128), 256, 0, stream>>>(fconv, depw, depb, convout);
    // --- attention message (MFMA; overwrites kB) ---
    attn_mfma<<<NROWS / 64, 256, 0, stream>>>(qB, KVg, Ksg, msgattn);
    // --- merge + LN1 ---
    gemm_big<256, 0, EPI_LN><<<g600, 512, 0, stream>>>(nullptr, msgattn, nullptr, wt_m, 256, msgB, nullptr, 256,
        nullptr, ln1w, ln1b, nullptr, nullptr, nullptr, nullptr, nullptr);
    // --- MLP1 + relu ---
    if (big) {
        gemm_big<256, 3, EPI_RELU><<<dim3(NROWS / 128, 2), 512, 0, stream>>>(nullptr, xb, msgB, wt_m1, 512, hidden, nullptr, 512,
            nullptr, nullptr, nullptr, nullptr, nullptr, nullptr, nullptr, nullptr);
    } else {
        gemm_big<256, 2, EPI_RELU><<<dim3(NROWS / 128, 2), 512, 0, stream>>>(x, nullptr, msgB, wt_m1, 512, hidden, nullptr, 512,
            nullptr, nullptr, nullptr, nullptr, nullptr, nullptr, nullptr, nullptr);
    }
    // --- MLP2 + LN2 ---
    gemm_big<256, 0, EPI_LN><<<g600, 512, 0, stream>>>(nullptr, hidden, nullptr, wt_m2, 512, msg2, nullptr, 256,
        nullptr, ln2w, ln2b, nullptr, nullptr, nullptr, nullptr, nullptr);
    // --- adapter down + relu ---
    if (big) {
        gemm_big<64, 3, EPI_RELU><<<g600, 512, 0, stream>>>(nullptr, xb, msg2, wt_d, 512, h2, nullptr, 64,
            nullptr, nullptr, nullptr, nullptr, nullptr, nullptr, nullptr, nullptr);
    } else {
        gemm_big<64, 2, EPI_RELU><<<g600, 512, 0, stream>>>(x, nullptr, msg2, wt_d, 512, h2, nullptr, 64,
            nullptr, nullptr, nullptr, nullptr, nullptr, nullptr, nullptr, nullptr);
    }
    // --- adapter up + final combine ---
    gemm_big<256, 0, EPI_FINAL><<<g600, 512, 0, stream>>>(nullptr, h2, nullptr, wt_u, 64, nullptr, (float*)d_out, 256,
        nullptr, nullptr, nullptr, x, big ? xb : nullptr, msg2, convout, rate);
}